// Round 5
// baseline (434.890 us; speedup 1.0000x reference)
//
#include <hip/hip_runtime.h>
#include <hip/hip_bf16.h>
#include <math.h>

#define DI __device__ __forceinline__

constexpr int NN   = 20000;
constexpr int NE   = 160000;
constexpr int FIN  = 64;
constexpr int HIDC = 256;
constexpr int NH   = 4;
constexpr int NOUT = 3328;   // 3*1024 (QKV) + 256 (skip)
constexpr int CAPD = 128;    // per-node edge index stash capacity

typedef __attribute__((ext_vector_type(8))) short short8;
typedef __attribute__((ext_vector_type(4))) float f32x4;
typedef __attribute__((ext_vector_type(2))) float f32x2;

DI float bf2f(unsigned short u) { return __uint_as_float(((unsigned)u) << 16); }

DI unsigned fp8pack4(float a, float b, float c, float d) {
  int v = __builtin_amdgcn_cvt_pk_fp8_f32(a, b, 0, false);
  v = __builtin_amdgcn_cvt_pk_fp8_f32(c, d, v, true);
  return (unsigned)v;
}

// ---------------- merged input cast + degree count ----------------
__global__ void k_prep(const float* __restrict__ x, __hip_bfloat16* __restrict__ xb,
                       const int* __restrict__ dst, int* __restrict__ deg) {
  int gid = blockIdx.x * 256 + threadIdx.x;
  if (gid < NN * FIN) xb[gid] = __float2bfloat16(x[gid]);
  if (gid < NE) atomicAdd(&deg[dst[gid]], 1);
}

__global__ void k_scan(const int* __restrict__ deg, int* __restrict__ offs,
                       int* __restrict__ cursor, int n_) {
  __shared__ int part[1024];
  int tid = threadIdx.x;
  const int CH = (n_ + 1023) >> 10;
  int base = tid * CH;
  int s = 0;
  for (int i = 0; i < CH; ++i) { int idx = base + i; if (idx < n_) s += deg[idx]; }
  part[tid] = s;
  __syncthreads();
  for (int off = 1; off < 1024; off <<= 1) {
    int v = (tid >= off) ? part[tid - off] : 0;
    __syncthreads();
    part[tid] += v;
    __syncthreads();
  }
  int run = (tid == 0) ? 0 : part[tid - 1];
  for (int i = 0; i < CH; ++i) {
    int idx = base + i;
    if (idx < n_) { offs[idx] = run; cursor[idx] = run; run += deg[idx]; }
  }
  if (tid == 1023) offs[n_] = run;
}

__global__ void k_scatter(const int* __restrict__ dst, int* __restrict__ cursor,
                          int* __restrict__ eid, int e_) {
  int e = blockIdx.x * blockDim.x + threadIdx.x;
  if (e < e_) {
    int p = atomicAdd(&cursor[dst[e]], 1);
    eid[p] = e;
  }
}

// ---------------- weight pack: Wt[n][k] = concat(wq|wk|wv|ws)[k][n], bf16 ----------------
template <int K>
__global__ void k_pack(const float* __restrict__ wq, const float* __restrict__ bq,
                       const float* __restrict__ wk, const float* __restrict__ bk,
                       const float* __restrict__ wv, const float* __restrict__ bv,
                       const float* __restrict__ ws, const float* __restrict__ bs,
                       __hip_bfloat16* __restrict__ Wt, float* __restrict__ biasp) {
  int n = blockIdx.x * 128 + threadIdx.x;  // 0..3327
  int k = blockIdx.y;                      // 0..K-1
  const float* w; const float* b; int off; int M;
  if (n < 1024)      { w = wq; b = bq; off = n;        M = 1024; }
  else if (n < 2048) { w = wk; b = bk; off = n - 1024; M = 1024; }
  else if (n < 3072) { w = wv; b = bv; off = n - 2048; M = 1024; }
  else               { w = ws; b = bs; off = n - 3072; M = 256;  }
  Wt[(size_t)n * K + k] = __float2bfloat16(w[(size_t)k * M + off]);
  if (k == 0) biasp[n] = b[off];
}

// ---------------- register-direct MFMA GEMM -> q/k/v fp8 | skip bf16 ----------------
// No LDS staging, no barriers: fragments load straight from global (L2-resident),
// per-wave-private LDS only for the transpose epilogue.
template <int K>
__global__ __launch_bounds__(256) void k_gemm_reg(
    const __hip_bfloat16* __restrict__ X, const __hip_bfloat16* __restrict__ Wt,
    const float* __restrict__ biasp,
    unsigned char* __restrict__ qb, unsigned char* __restrict__ kb,
    unsigned char* __restrict__ vb, __hip_bfloat16* __restrict__ skipb,
    int nrows, int RB, int CB) {
  __shared__ char eplds[36864];  // 4 waves x 9216B (64 rows x 144B)
  const int tid = threadIdx.x;

  // bijective XCD chunk swizzle
  const int nwg = RB * CB;
  int bid = blockIdx.x;
  {
    int q8 = nwg >> 3, r8 = nwg & 7;
    int xcd = bid & 7, idx = bid >> 3;
    bid = (xcd < r8 ? xcd * (q8 + 1) : r8 * (q8 + 1) + (xcd - r8) * q8) + idx;
  }
  const int bm = (bid / CB) * 128;
  const int bn = (bid % CB) * 128;
  constexpr int KT = K / 32;

  const int l = tid & 63, w = tid >> 6;
  const int wr = w >> 1, wc = w & 1;
  const int lm = l & 15, lk = l >> 4;

  const __hip_bfloat16* Ap[4];
  const __hip_bfloat16* Bp[4];
#pragma unroll
  for (int m = 0; m < 4; ++m) {
    int row = bm + wr * 64 + m * 16 + lm;
    if (row >= nrows) row = nrows - 1;
    Ap[m] = X + (size_t)row * K + lk * 8;
  }
#pragma unroll
  for (int n = 0; n < 4; ++n) {
    int col = bn + wc * 64 + n * 16 + lm;
    Bp[n] = Wt + (size_t)col * K + lk * 8;
  }

  f32x4 acc[4][4] = {};
#pragma unroll 2
  for (int kt = 0; kt < KT; ++kt) {
    short8 a[4], b[4];
#pragma unroll
    for (int m = 0; m < 4; ++m) a[m] = *(const short8*)(Ap[m] + kt * 32);
#pragma unroll
    for (int n = 0; n < 4; ++n) b[n] = *(const short8*)(Bp[n] + kt * 32);
#pragma unroll
    for (int m = 0; m < 4; ++m)
#pragma unroll
      for (int n = 0; n < 4; ++n)
        acc[m][n] = __builtin_amdgcn_mfma_f32_16x16x32_bf16(a[m], b[n], acc[m][n], 0, 0, 0);
  }

  // epilogue: per-wave-private LDS transpose (no cross-wave hazard -> no barrier)
  char* ep = eplds + w * 9216;
  float bia[4];
#pragma unroll
  for (int n = 0; n < 4; ++n) bia[n] = biasp[bn + wc * 64 + n * 16 + lm];
#pragma unroll
  for (int m = 0; m < 4; ++m)
#pragma unroll
    for (int n = 0; n < 4; ++n)
#pragma unroll
      for (int r = 0; r < 4; ++r) {
        int rl = m * 16 + lk * 4 + r;
        int cl = n * 16 + lm;
        *(__hip_bfloat16*)(ep + rl * 144 + cl * 2) = __float2bfloat16(acc[m][n][r] + bia[n]);
      }
  const int c8 = l & 7;   // 8 lanes per row, 8 cols (16B) each
  const int r8 = l >> 3;
#pragma unroll
  for (int it = 0; it < 8; ++it) {
    int rl = it * 8 + r8;
    int grow = bm + wr * 64 + rl;
    if (grow >= nrows) continue;
    short8 t = *(const short8*)(ep + rl * 144 + c8 * 16);
    int colg = bn + wc * 64 + c8 * 8;
    if (colg < 3072) {
      float f0 = bf2f((unsigned short)t[0]), f1 = bf2f((unsigned short)t[1]);
      float f2 = bf2f((unsigned short)t[2]), f3 = bf2f((unsigned short)t[3]);
      float f4 = bf2f((unsigned short)t[4]), f5 = bf2f((unsigned short)t[5]);
      float f6 = bf2f((unsigned short)t[6]), f7 = bf2f((unsigned short)t[7]);
      uint2 d;
      d.x = fp8pack4(f0, f1, f2, f3);
      d.y = fp8pack4(f4, f5, f6, f7);
      if (colg < 1024)      *(uint2*)(qb + (size_t)grow * 1024 + colg)        = d;
      else if (colg < 2048) *(uint2*)(kb + (size_t)grow * 1024 + colg - 1024) = d;
      else                  *(uint2*)(vb + (size_t)grow * 1024 + colg - 2048) = d;
    } else {
      *(short8*)((__hip_bfloat16*)skipb + (size_t)grow * HIDC + colg - 3072) = t;
    }
  }
}

// ---------------- fused single-pass attention (fp8 q/k/v, bf16 skip) ----------------
__global__ __launch_bounds__(256) void k_attn(
    const unsigned char* __restrict__ qb, const unsigned char* __restrict__ kb,
    const unsigned char* __restrict__ vb,
    const int* __restrict__ offs, const int* __restrict__ eid,
    const int* __restrict__ src, const __hip_bfloat16* __restrict__ skipb,
    __hip_bfloat16* __restrict__ outb, float* __restrict__ outf) {
  int n = blockIdx.x;
  int s0 = offs[n], s1 = offs[n + 1];
  int deg = s1 - s0;
  int tid = threadIdx.x;
  if (deg == 0) {  // out = skip
    if (tid < 64) {
      int c = tid * 4;
      ushort4 sv = *(const ushort4*)((const ushort*)skipb + (size_t)n * HIDC + c);
      if (outb != nullptr) *(ushort4*)((ushort*)outb + (size_t)n * HIDC + c) = sv;
      if (outf != nullptr) {
        float* xr = outf + (size_t)n * HIDC + c;
        xr[0] = bf2f(sv.x); xr[1] = bf2f(sv.y); xr[2] = bf2f(sv.z); xr[3] = bf2f(sv.w);
      }
    }
    return;
  }
  __shared__ int ses[CAPD];
  __shared__ float red[NH][HIDC];
  int h = tid >> 6, lane = tid & 63;
  int dc = deg < CAPD ? deg : CAPD;
  for (int i = tid; i < dc; i += 256) ses[i] = src[eid[s0 + i]];
  __syncthreads();

  const int hc = h * HIDC;
  int c = lane * 4;
  unsigned qu = *(const unsigned*)(qb + (size_t)n * 1024 + hc + c);
  f32x2 q01 = __builtin_amdgcn_cvt_pk_f32_fp8(qu, false);
  f32x2 q23 = __builtin_amdgcn_cvt_pk_f32_fp8(qu, true);
  float qx = q01.x, qy = q01.y, qz = q23.x, qw = q23.y;

  float denom = 0.f;
  float4 acc = make_float4(0.f, 0.f, 0.f, 0.f);
  // 2-deep software pipeline over the serial edge loop
  int sc0 = ses[0];
  unsigned ku0 = *(const unsigned*)(kb + (size_t)sc0 * 1024 + hc + c);
  unsigned vu0 = *(const unsigned*)(vb + (size_t)sc0 * 1024 + hc + c);
  for (int i = 0; i < deg; ++i) {
    unsigned ku1 = 0, vu1 = 0;
    if (i + 1 < deg) {
      int s1i = (i + 1 < CAPD) ? ses[i + 1] : src[eid[s0 + i + 1]];
      ku1 = *(const unsigned*)(kb + (size_t)s1i * 1024 + hc + c);
      vu1 = *(const unsigned*)(vb + (size_t)s1i * 1024 + hc + c);
    }
    f32x2 k01 = __builtin_amdgcn_cvt_pk_f32_fp8(ku0, false);
    f32x2 k23 = __builtin_amdgcn_cvt_pk_f32_fp8(ku0, true);
    float p = qx * k01.x + qy * k01.y + qz * k23.x + qw * k23.y;
#pragma unroll
    for (int off = 32; off > 0; off >>= 1) p += __shfl_xor(p, off);
    float wgt = __expf(p * 0.0625f);
    denom += wgt;
    f32x2 v01 = __builtin_amdgcn_cvt_pk_f32_fp8(vu0, false);
    f32x2 v23 = __builtin_amdgcn_cvt_pk_f32_fp8(vu0, true);
    acc.x = fmaf(wgt, v01.x, acc.x);
    acc.y = fmaf(wgt, v01.y, acc.y);
    acc.z = fmaf(wgt, v23.x, acc.z);
    acc.w = fmaf(wgt, v23.y, acc.w);
    ku0 = ku1; vu0 = vu1;
  }
  float dinv = 1.f / (denom + 1e-16f);
  red[h][c + 0] = acc.x * dinv;
  red[h][c + 1] = acc.y * dinv;
  red[h][c + 2] = acc.z * dinv;
  red[h][c + 3] = acc.w * dinv;
  __syncthreads();
  if (tid < 64) {
    int c0 = tid * 4;
    ushort4 sv = *(const ushort4*)((const ushort*)skipb + (size_t)n * HIDC + c0);
    float sk[4] = {bf2f(sv.x), bf2f(sv.y), bf2f(sv.z), bf2f(sv.w)};
#pragma unroll
    for (int j = 0; j < 4; ++j) {
      float m = (red[0][c0 + j] + red[1][c0 + j] + red[2][c0 + j] + red[3][c0 + j]) * 0.25f;
      float val = m + sk[j];
      if (outb != nullptr) ((ushort*)outb)[(size_t)n * HIDC + c0 + j] = (ushort)(__bfloat16_as_ushort(__float2bfloat16(val)));
      if (outf != nullptr) outf[(size_t)n * HIDC + c0 + j] = val;
    }
  }
}

// ---------------- batch norm stats ----------------
__global__ void k_bnstats(const float* __restrict__ x, float* __restrict__ sums,
                          float* __restrict__ sumsq, int n_) {
  int t = threadIdx.x;
  float s = 0.f, s2 = 0.f;
  for (int r = blockIdx.x; r < n_; r += gridDim.x) {
    float vv = x[(size_t)r * HIDC + t];
    s += vv; s2 += vv * vv;
  }
  atomicAdd(&sums[t], s);
  atomicAdd(&sumsq[t], s2);
}

// ---------------- BN apply (stats inline) + linear head + softmax + rsu row ------
__global__ __launch_bounds__(256) void k_final(
    const float* __restrict__ x, const float* __restrict__ sums, const float* __restrict__ sumsq,
    const float* __restrict__ gamma, const float* __restrict__ beta,
    const float* __restrict__ lw, const float* __restrict__ lb,
    float* __restrict__ out, int n_) {
  int sub = threadIdx.x >> 6, lane = threadIdx.x & 63;
  int n = blockIdx.x * 4 + sub;
  if (n >= n_) return;
  int c = lane * 4;
  float4 sm  = *(const float4*)(sums + c);
  float4 sq  = *(const float4*)(sumsq + c);
  const float inv_n = 1.f / (float)n_;
  float mu0 = sm.x * inv_n, mu1 = sm.y * inv_n, mu2 = sm.z * inv_n, mu3 = sm.w * inv_n;
  float r0 = 1.f / sqrtf(fmaxf(sq.x * inv_n - mu0 * mu0, 0.f) + 1e-5f);
  float r1 = 1.f / sqrtf(fmaxf(sq.y * inv_n - mu1 * mu1, 0.f) + 1e-5f);
  float r2 = 1.f / sqrtf(fmaxf(sq.z * inv_n - mu2 * mu2, 0.f) + 1e-5f);
  float r3 = 1.f / sqrtf(fmaxf(sq.w * inv_n - mu3 * mu3, 0.f) + 1e-5f);
  const float* xr = x + (size_t)n * HIDC;
  float4 xv = *(const float4*)(xr + c);
  float4 gv = *(const float4*)(gamma + c);
  float4 bv = *(const float4*)(beta + c);
  float y0 = gv.x * (xv.x - mu0) * r0 + bv.x;
  float y1 = gv.y * (xv.y - mu1) * r1 + bv.y;
  float y2 = gv.z * (xv.z - mu2) * r2 + bv.z;
  float y3 = gv.w * (xv.w - mu3) * r3 + bv.w;
  float4 wa = *(const float4*)(lw + (size_t)c * 2);
  float4 wb = *(const float4*)(lw + (size_t)c * 2 + 4);
  float p0 = y0 * wa.x + y1 * wa.z + y2 * wb.x + y3 * wb.z;
  float p1 = y0 * wa.y + y1 * wa.w + y2 * wb.y + y3 * wb.w;
#pragma unroll
  for (int off = 32; off > 0; off >>= 1) {
    p0 += __shfl_xor(p0, off);
    p1 += __shfl_xor(p1, off);
  }
  if (n == 0) *(float4*)(out + (size_t)NN * 2 + c) = make_float4(y0, y1, y2, y3);
  if (lane == 0) {
    float l0 = fmaxf(p0 + lb[0], 0.f);
    float l1 = fmaxf(p1 + lb[1], 0.f);
    float m = fmaxf(l0, l1);
    float e0 = expf(l0 - m), e1 = expf(l1 - m);
    float inv = 1.f / (e0 + e1);
    out[(size_t)n * 2 + 0] = e0 * inv;
    out[(size_t)n * 2 + 1] = e1 * inv;
  }
}

// ---------------- launch ----------------
extern "C" void kernel_launch(void* const* d_in, const int* in_sizes, int n_in,
                              void* d_out, int out_size, void* d_ws, size_t ws_size,
                              hipStream_t stream) {
  const float* x0  = (const float*)d_in[0];
  const int*   ei  = (const int*)d_in[1];
  const float* wq1 = (const float*)d_in[2];  const float* bq1 = (const float*)d_in[3];
  const float* wk1 = (const float*)d_in[4];  const float* bk1 = (const float*)d_in[5];
  const float* wv1 = (const float*)d_in[6];  const float* bv1 = (const float*)d_in[7];
  const float* ws1 = (const float*)d_in[8];  const float* bs1 = (const float*)d_in[9];
  const float* wq2 = (const float*)d_in[10]; const float* bq2 = (const float*)d_in[11];
  const float* wk2 = (const float*)d_in[12]; const float* bk2 = (const float*)d_in[13];
  const float* wv2 = (const float*)d_in[14]; const float* bv2 = (const float*)d_in[15];
  const float* ws2 = (const float*)d_in[16]; const float* bs2 = (const float*)d_in[17];
  const float* gam = (const float*)d_in[18]; const float* bet = (const float*)d_in[19];
  const float* lw  = (const float*)d_in[20]; const float* lb  = (const float*)d_in[21];
  const int* srcv = ei;
  const int* dstv = ei + NE;

  char* p = (char*)d_ws;
  auto take = [&](size_t bytes) {
    char* r = p;
    p += (bytes + 255) & ~(size_t)255;
    return r;
  };
  unsigned char* qbuf = (unsigned char*)take((size_t)NN * 1024);
  unsigned char* kbuf = (unsigned char*)take((size_t)NN * 1024);
  unsigned char* vbuf = (unsigned char*)take((size_t)NN * 1024);
  __hip_bfloat16* skipb = (__hip_bfloat16*)take((size_t)NN * HIDC * 2);
  __hip_bfloat16* x0b = (__hip_bfloat16*)take((size_t)NN * FIN * 2);
  __hip_bfloat16* x2b = (__hip_bfloat16*)take((size_t)NN * HIDC * 2);
  __hip_bfloat16* Wt  = (__hip_bfloat16*)take((size_t)NOUT * HIDC * 2);
  float* x3    = (float*)take((size_t)NN * HIDC * 4);
  float* biasp = (float*)take((size_t)NOUT * 4);
  float* bnbuf = (float*)take(2 * HIDC * 4);
  int* deg    = (int*)take((size_t)NN * 4);
  int* offs   = (int*)take((size_t)(NN + 1) * 4);
  int* cursor = (int*)take((size_t)NN * 4);
  int* eidb   = (int*)take((size_t)NE * 4);
  if ((size_t)(p - (char*)d_ws) > ws_size) return;

  float* sums  = bnbuf;
  float* sumsq = bnbuf + HIDC;

  hipMemsetAsync(deg, 0, (size_t)NN * 4, stream);
  hipMemsetAsync(bnbuf, 0, 2 * HIDC * 4, stream);
  k_prep<<<(NN * FIN + 255) / 256, 256, 0, stream>>>(x0, x0b, dstv, deg);
  k_scan<<<1, 1024, 0, stream>>>(deg, offs, cursor, NN);
  k_scatter<<<(NE + 255) / 256, 256, 0, stream>>>(dstv, cursor, eidb, NE);

  const int RB = (NN + 127) / 128;  // 157
  const int CB = NOUT / 128;        // 26
  // ---- layer 1 ----
  k_pack<FIN><<<dim3(CB, FIN), 128, 0, stream>>>(wq1, bq1, wk1, bk1, wv1, bv1, ws1, bs1, Wt, biasp);
  k_gemm_reg<FIN><<<RB * CB, 256, 0, stream>>>(x0b, Wt, biasp, qbuf, kbuf, vbuf, skipb, NN, RB, CB);
  k_attn<<<NN, 256, 0, stream>>>(qbuf, kbuf, vbuf, offs, eidb, srcv, skipb, x2b, nullptr);
  // ---- layer 2 ----
  k_pack<HIDC><<<dim3(CB, HIDC), 128, 0, stream>>>(wq2, bq2, wk2, bk2, wv2, bv2, ws2, bs2, Wt, biasp);
  k_gemm_reg<HIDC><<<RB * CB, 256, 0, stream>>>(x2b, Wt, biasp, qbuf, kbuf, vbuf, skipb, NN, RB, CB);
  k_attn<<<NN, 256, 0, stream>>>(qbuf, kbuf, vbuf, offs, eidb, srcv, skipb, nullptr, x3);
  // ---- BN + head ----
  k_bnstats<<<256, 256, 0, stream>>>(x3, sums, sumsq, NN);
  k_final<<<(NN + 3) / 4, 256, 0, stream>>>(x3, sums, sumsq, gam, bet, lw, lb, (float*)d_out, NN);
}

// Round 6
// 396.877 us; speedup vs baseline: 1.0958x; 1.0958x over previous
//
#include <hip/hip_runtime.h>
#include <hip/hip_bf16.h>
#include <math.h>

#define DI __device__ __forceinline__

constexpr int NN   = 20000;
constexpr int NE   = 160000;
constexpr int FIN  = 64;
constexpr int HIDC = 256;
constexpr int NH   = 4;
constexpr int NOUT = 3328;   // 3*1024 (QKV) + 256 (skip)
constexpr int CAPD = 128;    // per-node edge index stash capacity

typedef __attribute__((ext_vector_type(8))) short short8;
typedef __attribute__((ext_vector_type(4))) float f32x4;
typedef __attribute__((ext_vector_type(2))) float f32x2;

DI float bf2f(unsigned short u) { return __uint_as_float(((unsigned)u) << 16); }

DI void gld16(const void* g, void* l) {
  __builtin_amdgcn_global_load_lds((const __attribute__((address_space(1))) unsigned*)g,
                                   (__attribute__((address_space(3))) unsigned*)l, 16, 0, 0);
}

DI unsigned fp8pack4(float a, float b, float c, float d) {
  int v = __builtin_amdgcn_cvt_pk_fp8_f32(a, b, 0, false);
  v = __builtin_amdgcn_cvt_pk_fp8_f32(c, d, v, true);
  return (unsigned)v;
}

// ---------------- merged input cast + degree count ----------------
__global__ void k_prep(const float* __restrict__ x, __hip_bfloat16* __restrict__ xb,
                       const int* __restrict__ dst, int* __restrict__ deg) {
  int gid = blockIdx.x * 256 + threadIdx.x;
  if (gid < NN * FIN) xb[gid] = __float2bfloat16(x[gid]);
  if (gid < NE) atomicAdd(&deg[dst[gid]], 1);
}

__global__ void k_scan(const int* __restrict__ deg, int* __restrict__ offs,
                       int* __restrict__ cursor, int n_) {
  __shared__ int part[1024];
  int tid = threadIdx.x;
  const int CH = (n_ + 1023) >> 10;
  int base = tid * CH;
  int s = 0;
  for (int i = 0; i < CH; ++i) { int idx = base + i; if (idx < n_) s += deg[idx]; }
  part[tid] = s;
  __syncthreads();
  for (int off = 1; off < 1024; off <<= 1) {
    int v = (tid >= off) ? part[tid - off] : 0;
    __syncthreads();
    part[tid] += v;
    __syncthreads();
  }
  int run = (tid == 0) ? 0 : part[tid - 1];
  for (int i = 0; i < CH; ++i) {
    int idx = base + i;
    if (idx < n_) { offs[idx] = run; cursor[idx] = run; run += deg[idx]; }
  }
  if (tid == 1023) offs[n_] = run;
}

__global__ void k_scatter(const int* __restrict__ dst, int* __restrict__ cursor,
                          int* __restrict__ eid, int e_) {
  int e = blockIdx.x * blockDim.x + threadIdx.x;
  if (e < e_) {
    int p = atomicAdd(&cursor[dst[e]], 1);
    eid[p] = e;
  }
}

// ---------------- weight pack: Wt[n][k] = concat(wq|wk|wv|ws)[k][n], bf16 ----------------
template <int K>
__global__ void k_pack(const float* __restrict__ wq, const float* __restrict__ bq,
                       const float* __restrict__ wk, const float* __restrict__ bk,
                       const float* __restrict__ wv, const float* __restrict__ bv,
                       const float* __restrict__ ws, const float* __restrict__ bs,
                       __hip_bfloat16* __restrict__ Wt, float* __restrict__ biasp) {
  int n = blockIdx.x * 128 + threadIdx.x;  // 0..3327
  int k = blockIdx.y;                      // 0..K-1
  const float* w; const float* b; int off; int M;
  if (n < 1024)      { w = wq; b = bq; off = n;        M = 1024; }
  else if (n < 2048) { w = wk; b = bk; off = n - 1024; M = 1024; }
  else if (n < 3072) { w = wv; b = bv; off = n - 2048; M = 1024; }
  else               { w = ws; b = bs; off = n - 3072; M = 256;  }
  Wt[(size_t)n * K + k] = __float2bfloat16(w[(size_t)k * M + off]);
  if (k == 0) biasp[n] = b[off];
}

// ---------------- multi-tile staged MFMA GEMM -> q/k/v fp8 | skip bf16 ----------------
// Each block owns one 128-col tile and sweeps TPC row-tiles; LDS-staged (gld_lds w16),
// double-buffered; epilogue reuses drained staging LDS as transpose scratch.
template <int K>
__global__ __launch_bounds__(256) void k_gemm_ms(
    const __hip_bfloat16* __restrict__ X, const __hip_bfloat16* __restrict__ Wt,
    const float* __restrict__ biasp,
    unsigned char* __restrict__ qb, unsigned char* __restrict__ kb,
    unsigned char* __restrict__ vb, __hip_bfloat16* __restrict__ skipb,
    int nrows, int CB, int NCH, int TPC, int RBtot) {
  __shared__ char lds[36864];  // dbuf 2x16KB; epilogue scratch 4x9216B
  const int tid = threadIdx.x;

  // bijective XCD chunk swizzle
  const int nwg = CB * NCH;
  int bid = blockIdx.x;
  {
    int q8 = nwg >> 3, r8 = nwg & 7;
    int xcd = bid & 7, idx = bid >> 3;
    bid = (xcd < r8 ? xcd * (q8 + 1) : r8 * (q8 + 1) + (xcd - r8) * q8) + idx;
  }
  const int bn = (bid % CB) * 128;
  const int chunk = bid / CB;
  const int tstart = chunk * TPC;
  const int tend = (tstart + TPC < RBtot) ? tstart + TPC : RBtot;
  constexpr int KT = K / 32;

  const int srow = tid & 127;
  const int kb0 = (tid >> 7) * 8;
  const int br = bn + srow;
  const __hip_bfloat16* bx = Wt + (size_t)br * K + kb0;

  const int l = tid & 63, w = tid >> 6;
  const int wr = w >> 1, wc = w & 1;
  const int lm = l & 15, lk = l >> 4;
  const int aoff = (lk * 128 + wr * 64 + lm) * 16;
  const int boff = 8192 + (lk * 128 + wc * 64 + lm) * 16;

  float bia[4];
#pragma unroll
  for (int n = 0; n < 4; ++n) bia[n] = biasp[bn + wc * 64 + n * 16 + lm];

  for (int t = tstart; t < tend; ++t) {
    const int bm = t * 128;
    int ar = bm + srow; if (ar >= nrows) ar = nrows - 1;
    const __hip_bfloat16* ax = X + (size_t)ar * K + kb0;

    auto STAGE = [&](int buf, int kt) {
      char* base = lds + buf * 16384;
      const int ko = kt * 32;
      gld16(ax + ko,      base + tid * 16);
      gld16(ax + ko + 16, base + 4096 + tid * 16);
      gld16(bx + ko,      base + 8192 + tid * 16);
      gld16(bx + ko + 16, base + 12288 + tid * 16);
    };

    f32x4 acc[4][4] = {};
    int cur = 0;
    STAGE(0, 0);
    __syncthreads();
#pragma unroll
    for (int kt = 0; kt < KT; ++kt) {
      if (kt + 1 < KT) STAGE(cur ^ 1, kt + 1);
      const char* base = lds + cur * 16384;
      short8 a[4], b[4];
#pragma unroll
      for (int m = 0; m < 4; ++m) a[m] = *(const short8*)(base + aoff + m * 256);
#pragma unroll
      for (int n = 0; n < 4; ++n) b[n] = *(const short8*)(base + boff + n * 256);
#pragma unroll
      for (int m = 0; m < 4; ++m)
#pragma unroll
        for (int n = 0; n < 4; ++n)
          acc[m][n] = __builtin_amdgcn_mfma_f32_16x16x32_bf16(a[m], b[n], acc[m][n], 0, 0, 0);
      __syncthreads();
      cur ^= 1;
    }

    // epilogue: per-wave LDS transpose (staging buffers are drained; regions private)
    char* ep = lds + w * 9216;
#pragma unroll
    for (int m = 0; m < 4; ++m)
#pragma unroll
      for (int n = 0; n < 4; ++n)
#pragma unroll
        for (int r = 0; r < 4; ++r) {
          int rl = m * 16 + lk * 4 + r;
          int cl = n * 16 + lm;
          *(__hip_bfloat16*)(ep + rl * 144 + cl * 2) = __float2bfloat16(acc[m][n][r] + bia[n]);
        }
    const int c8 = l & 7;   // 8 lanes per row, 8 cols (16B) each
    const int r8 = l >> 3;
#pragma unroll
    for (int it = 0; it < 8; ++it) {
      int rl = it * 8 + r8;
      int grow = bm + wr * 64 + rl;
      if (grow >= nrows) continue;
      short8 tv = *(const short8*)(ep + rl * 144 + c8 * 16);
      int colg = bn + wc * 64 + c8 * 8;
      if (colg < 3072) {
        float f0 = bf2f((unsigned short)tv[0]), f1 = bf2f((unsigned short)tv[1]);
        float f2 = bf2f((unsigned short)tv[2]), f3 = bf2f((unsigned short)tv[3]);
        float f4 = bf2f((unsigned short)tv[4]), f5 = bf2f((unsigned short)tv[5]);
        float f6 = bf2f((unsigned short)tv[6]), f7 = bf2f((unsigned short)tv[7]);
        uint2 d;
        d.x = fp8pack4(f0, f1, f2, f3);
        d.y = fp8pack4(f4, f5, f6, f7);
        if (colg < 1024)      *(uint2*)(qb + (size_t)grow * 1024 + colg)        = d;
        else if (colg < 2048) *(uint2*)(kb + (size_t)grow * 1024 + colg - 1024) = d;
        else                  *(uint2*)(vb + (size_t)grow * 1024 + colg - 2048) = d;
      } else {
        *(short8*)((__hip_bfloat16*)skipb + (size_t)grow * HIDC + colg - 3072) = tv;
      }
    }
    __syncthreads();  // epilogue LDS reads done before next tile's staging
  }
}

// ---------------- fused single-pass attention (fp8 q/k/v, bf16 skip) ----------------
__global__ __launch_bounds__(256) void k_attn(
    const unsigned char* __restrict__ qb, const unsigned char* __restrict__ kb,
    const unsigned char* __restrict__ vb,
    const int* __restrict__ offs, const int* __restrict__ eid,
    const int* __restrict__ src, const __hip_bfloat16* __restrict__ skipb,
    __hip_bfloat16* __restrict__ outb, float* __restrict__ outf) {
  int n = blockIdx.x;
  int s0 = offs[n], s1 = offs[n + 1];
  int deg = s1 - s0;
  int tid = threadIdx.x;
  if (deg == 0) {  // out = skip
    if (tid < 64) {
      int c = tid * 4;
      ushort4 sv = *(const ushort4*)((const ushort*)skipb + (size_t)n * HIDC + c);
      if (outb != nullptr) *(ushort4*)((ushort*)outb + (size_t)n * HIDC + c) = sv;
      if (outf != nullptr) {
        float* xr = outf + (size_t)n * HIDC + c;
        xr[0] = bf2f(sv.x); xr[1] = bf2f(sv.y); xr[2] = bf2f(sv.z); xr[3] = bf2f(sv.w);
      }
    }
    return;
  }
  __shared__ int ses[CAPD];
  __shared__ float red[NH][HIDC];
  int h = tid >> 6, lane = tid & 63;
  int dc = deg < CAPD ? deg : CAPD;
  for (int i = tid; i < dc; i += 256) ses[i] = src[eid[s0 + i]];
  __syncthreads();

  const int hc = h * HIDC;
  int c = lane * 4;
  unsigned qu = *(const unsigned*)(qb + (size_t)n * 1024 + hc + c);
  f32x2 q01 = __builtin_amdgcn_cvt_pk_f32_fp8(qu, false);
  f32x2 q23 = __builtin_amdgcn_cvt_pk_f32_fp8(qu, true);
  float qx = q01.x, qy = q01.y, qz = q23.x, qw = q23.y;

  float denom = 0.f;
  float4 acc = make_float4(0.f, 0.f, 0.f, 0.f);
  // 2-deep software pipeline over the serial edge loop
  int sc0 = ses[0];
  unsigned ku0 = *(const unsigned*)(kb + (size_t)sc0 * 1024 + hc + c);
  unsigned vu0 = *(const unsigned*)(vb + (size_t)sc0 * 1024 + hc + c);
  for (int i = 0; i < deg; ++i) {
    unsigned ku1 = 0, vu1 = 0;
    if (i + 1 < deg) {
      int s1i = (i + 1 < CAPD) ? ses[i + 1] : src[eid[s0 + i + 1]];
      ku1 = *(const unsigned*)(kb + (size_t)s1i * 1024 + hc + c);
      vu1 = *(const unsigned*)(vb + (size_t)s1i * 1024 + hc + c);
    }
    f32x2 k01 = __builtin_amdgcn_cvt_pk_f32_fp8(ku0, false);
    f32x2 k23 = __builtin_amdgcn_cvt_pk_f32_fp8(ku0, true);
    float p = qx * k01.x + qy * k01.y + qz * k23.x + qw * k23.y;
#pragma unroll
    for (int off = 32; off > 0; off >>= 1) p += __shfl_xor(p, off);
    float wgt = __expf(p * 0.0625f);
    denom += wgt;
    f32x2 v01 = __builtin_amdgcn_cvt_pk_f32_fp8(vu0, false);
    f32x2 v23 = __builtin_amdgcn_cvt_pk_f32_fp8(vu0, true);
    acc.x = fmaf(wgt, v01.x, acc.x);
    acc.y = fmaf(wgt, v01.y, acc.y);
    acc.z = fmaf(wgt, v23.x, acc.z);
    acc.w = fmaf(wgt, v23.y, acc.w);
    ku0 = ku1; vu0 = vu1;
  }
  float dinv = 1.f / (denom + 1e-16f);
  red[h][c + 0] = acc.x * dinv;
  red[h][c + 1] = acc.y * dinv;
  red[h][c + 2] = acc.z * dinv;
  red[h][c + 3] = acc.w * dinv;
  __syncthreads();
  if (tid < 64) {
    int c0 = tid * 4;
    ushort4 sv = *(const ushort4*)((const ushort*)skipb + (size_t)n * HIDC + c0);
    float sk[4] = {bf2f(sv.x), bf2f(sv.y), bf2f(sv.z), bf2f(sv.w)};
#pragma unroll
    for (int j = 0; j < 4; ++j) {
      float m = (red[0][c0 + j] + red[1][c0 + j] + red[2][c0 + j] + red[3][c0 + j]) * 0.25f;
      float val = m + sk[j];
      if (outb != nullptr) ((ushort*)outb)[(size_t)n * HIDC + c0 + j] = (ushort)(__bfloat16_as_ushort(__float2bfloat16(val)));
      if (outf != nullptr) outf[(size_t)n * HIDC + c0 + j] = val;
    }
  }
}

// ---------------- batch norm stats ----------------
__global__ void k_bnstats(const float* __restrict__ x, float* __restrict__ sums,
                          float* __restrict__ sumsq, int n_) {
  int t = threadIdx.x;
  float s = 0.f, s2 = 0.f;
  for (int r = blockIdx.x; r < n_; r += gridDim.x) {
    float vv = x[(size_t)r * HIDC + t];
    s += vv; s2 += vv * vv;
  }
  atomicAdd(&sums[t], s);
  atomicAdd(&sumsq[t], s2);
}

// ---------------- BN apply (stats inline) + linear head + softmax + rsu row ------
__global__ __launch_bounds__(256) void k_final(
    const float* __restrict__ x, const float* __restrict__ sums, const float* __restrict__ sumsq,
    const float* __restrict__ gamma, const float* __restrict__ beta,
    const float* __restrict__ lw, const float* __restrict__ lb,
    float* __restrict__ out, int n_) {
  int sub = threadIdx.x >> 6, lane = threadIdx.x & 63;
  int n = blockIdx.x * 4 + sub;
  if (n >= n_) return;
  int c = lane * 4;
  float4 sm  = *(const float4*)(sums + c);
  float4 sq  = *(const float4*)(sumsq + c);
  const float inv_n = 1.f / (float)n_;
  float mu0 = sm.x * inv_n, mu1 = sm.y * inv_n, mu2 = sm.z * inv_n, mu3 = sm.w * inv_n;
  float r0 = 1.f / sqrtf(fmaxf(sq.x * inv_n - mu0 * mu0, 0.f) + 1e-5f);
  float r1 = 1.f / sqrtf(fmaxf(sq.y * inv_n - mu1 * mu1, 0.f) + 1e-5f);
  float r2 = 1.f / sqrtf(fmaxf(sq.z * inv_n - mu2 * mu2, 0.f) + 1e-5f);
  float r3 = 1.f / sqrtf(fmaxf(sq.w * inv_n - mu3 * mu3, 0.f) + 1e-5f);
  const float* xr = x + (size_t)n * HIDC;
  float4 xv = *(const float4*)(xr + c);
  float4 gv = *(const float4*)(gamma + c);
  float4 bv = *(const float4*)(beta + c);
  float y0 = gv.x * (xv.x - mu0) * r0 + bv.x;
  float y1 = gv.y * (xv.y - mu1) * r1 + bv.y;
  float y2 = gv.z * (xv.z - mu2) * r2 + bv.z;
  float y3 = gv.w * (xv.w - mu3) * r3 + bv.w;
  float4 wa = *(const float4*)(lw + (size_t)c * 2);
  float4 wb = *(const float4*)(lw + (size_t)c * 2 + 4);
  float p0 = y0 * wa.x + y1 * wa.z + y2 * wb.x + y3 * wb.z;
  float p1 = y0 * wa.y + y1 * wa.w + y2 * wb.y + y3 * wb.w;
#pragma unroll
  for (int off = 32; off > 0; off >>= 1) {
    p0 += __shfl_xor(p0, off);
    p1 += __shfl_xor(p1, off);
  }
  if (n == 0) *(float4*)(out + (size_t)NN * 2 + c) = make_float4(y0, y1, y2, y3);
  if (lane == 0) {
    float l0 = fmaxf(p0 + lb[0], 0.f);
    float l1 = fmaxf(p1 + lb[1], 0.f);
    float m = fmaxf(l0, l1);
    float e0 = expf(l0 - m), e1 = expf(l1 - m);
    float inv = 1.f / (e0 + e1);
    out[(size_t)n * 2 + 0] = e0 * inv;
    out[(size_t)n * 2 + 1] = e1 * inv;
  }
}

// ---------------- launch ----------------
extern "C" void kernel_launch(void* const* d_in, const int* in_sizes, int n_in,
                              void* d_out, int out_size, void* d_ws, size_t ws_size,
                              hipStream_t stream) {
  const float* x0  = (const float*)d_in[0];
  const int*   ei  = (const int*)d_in[1];
  const float* wq1 = (const float*)d_in[2];  const float* bq1 = (const float*)d_in[3];
  const float* wk1 = (const float*)d_in[4];  const float* bk1 = (const float*)d_in[5];
  const float* wv1 = (const float*)d_in[6];  const float* bv1 = (const float*)d_in[7];
  const float* ws1 = (const float*)d_in[8];  const float* bs1 = (const float*)d_in[9];
  const float* wq2 = (const float*)d_in[10]; const float* bq2 = (const float*)d_in[11];
  const float* wk2 = (const float*)d_in[12]; const float* bk2 = (const float*)d_in[13];
  const float* wv2 = (const float*)d_in[14]; const float* bv2 = (const float*)d_in[15];
  const float* ws2 = (const float*)d_in[16]; const float* bs2 = (const float*)d_in[17];
  const float* gam = (const float*)d_in[18]; const float* bet = (const float*)d_in[19];
  const float* lw  = (const float*)d_in[20]; const float* lb  = (const float*)d_in[21];
  const int* srcv = ei;
  const int* dstv = ei + NE;

  char* p = (char*)d_ws;
  auto take = [&](size_t bytes) {
    char* r = p;
    p += (bytes + 255) & ~(size_t)255;
    return r;
  };
  unsigned char* qbuf = (unsigned char*)take((size_t)NN * 1024);
  unsigned char* kbuf = (unsigned char*)take((size_t)NN * 1024);
  unsigned char* vbuf = (unsigned char*)take((size_t)NN * 1024);
  __hip_bfloat16* skipb = (__hip_bfloat16*)take((size_t)NN * HIDC * 2);
  __hip_bfloat16* x0b = (__hip_bfloat16*)take((size_t)NN * FIN * 2);
  __hip_bfloat16* x2b = (__hip_bfloat16*)take((size_t)NN * HIDC * 2);
  __hip_bfloat16* Wt  = (__hip_bfloat16*)take((size_t)NOUT * HIDC * 2);
  float* x3    = (float*)take((size_t)NN * HIDC * 4);
  float* biasp = (float*)take((size_t)NOUT * 4);
  float* bnbuf = (float*)take(2 * HIDC * 4);
  int* deg    = (int*)take((size_t)NN * 4);
  int* offs   = (int*)take((size_t)(NN + 1) * 4);
  int* cursor = (int*)take((size_t)NN * 4);
  int* eidb   = (int*)take((size_t)NE * 4);
  if ((size_t)(p - (char*)d_ws) > ws_size) return;

  float* sums  = bnbuf;
  float* sumsq = bnbuf + HIDC;

  hipMemsetAsync(deg, 0, (size_t)NN * 4, stream);
  hipMemsetAsync(bnbuf, 0, 2 * HIDC * 4, stream);
  k_prep<<<(NN * FIN + 255) / 256, 256, 0, stream>>>(x0, x0b, dstv, deg);
  k_scan<<<1, 1024, 0, stream>>>(deg, offs, cursor, NN);
  k_scatter<<<(NE + 255) / 256, 256, 0, stream>>>(dstv, cursor, eidb, NE);

  const int RBt = (NN + 127) / 128;        // 157 row tiles
  const int CB  = NOUT / 128;              // 26 col tiles
  const int NCH = 40;                      // row chunks
  const int TPC = (RBt + NCH - 1) / NCH;   // 4 tiles per chunk
  const int GRID = CB * NCH;               // 1040 blocks
  // ---- layer 1 ----
  k_pack<FIN><<<dim3(CB, FIN), 128, 0, stream>>>(wq1, bq1, wk1, bk1, wv1, bv1, ws1, bs1, Wt, biasp);
  k_gemm_ms<FIN><<<GRID, 256, 0, stream>>>(x0b, Wt, biasp, qbuf, kbuf, vbuf, skipb, NN, CB, NCH, TPC, RBt);
  k_attn<<<NN, 256, 0, stream>>>(qbuf, kbuf, vbuf, offs, eidb, srcv, skipb, x2b, nullptr);
  // ---- layer 2 ----
  k_pack<HIDC><<<dim3(CB, HIDC), 128, 0, stream>>>(wq2, bq2, wk2, bk2, wv2, bv2, ws2, bs2, Wt, biasp);
  k_gemm_ms<HIDC><<<GRID, 256, 0, stream>>>(x2b, Wt, biasp, qbuf, kbuf, vbuf, skipb, NN, CB, NCH, TPC, RBt);
  k_attn<<<NN, 256, 0, stream>>>(qbuf, kbuf, vbuf, offs, eidb, srcv, skipb, nullptr, x3);
  // ---- BN + head ----
  k_bnstats<<<256, 256, 0, stream>>>(x3, sums, sumsq, NN);
  k_final<<<(NN + 3) / 4, 256, 0, stream>>>(x3, sums, sumsq, gam, bet, lw, lb, (float*)d_out, NN);
}

// Round 7
// 362.835 us; speedup vs baseline: 1.1986x; 1.0938x over previous
//
#include <hip/hip_runtime.h>
#include <hip/hip_bf16.h>
#include <math.h>

#define DI __device__ __forceinline__

constexpr int NN   = 20000;
constexpr int NE   = 160000;
constexpr int FIN  = 64;
constexpr int HIDC = 256;
constexpr int NH   = 4;
constexpr int NOUT = 3328;   // 3*1024 (QKV) + 256 (skip)
constexpr int CAPD = 128;    // per-node edge index stash capacity

typedef __attribute__((ext_vector_type(8))) short short8;
typedef __attribute__((ext_vector_type(4))) float f32x4;
typedef __attribute__((ext_vector_type(2))) float f32x2;

DI float bf2f(unsigned short u) { return __uint_as_float(((unsigned)u) << 16); }

DI void gld16(const void* g, void* l) {
  __builtin_amdgcn_global_load_lds((const __attribute__((address_space(1))) unsigned*)g,
                                   (__attribute__((address_space(3))) unsigned*)l, 16, 0, 0);
}

DI unsigned fp8pack4(float a, float b, float c, float d) {
  int v = __builtin_amdgcn_cvt_pk_fp8_f32(a, b, 0, false);
  v = __builtin_amdgcn_cvt_pk_fp8_f32(c, d, v, true);
  return (unsigned)v;
}

// ---------------- merged input cast + degree count ----------------
__global__ void k_prep(const float* __restrict__ x, __hip_bfloat16* __restrict__ xb,
                       const int* __restrict__ dst, int* __restrict__ deg) {
  int gid = blockIdx.x * 256 + threadIdx.x;
  if (gid < NN * FIN) xb[gid] = __float2bfloat16(x[gid]);
  if (gid < NE) atomicAdd(&deg[dst[gid]], 1);
}

__global__ void k_scan(const int* __restrict__ deg, int* __restrict__ offs,
                       int* __restrict__ cursor, int n_) {
  __shared__ int part[1024];
  int tid = threadIdx.x;
  const int CH = (n_ + 1023) >> 10;
  int base = tid * CH;
  int s = 0;
  for (int i = 0; i < CH; ++i) { int idx = base + i; if (idx < n_) s += deg[idx]; }
  part[tid] = s;
  __syncthreads();
  for (int off = 1; off < 1024; off <<= 1) {
    int v = (tid >= off) ? part[tid - off] : 0;
    __syncthreads();
    part[tid] += v;
    __syncthreads();
  }
  int run = (tid == 0) ? 0 : part[tid - 1];
  for (int i = 0; i < CH; ++i) {
    int idx = base + i;
    if (idx < n_) { offs[idx] = run; cursor[idx] = run; run += deg[idx]; }
  }
  if (tid == 1023) offs[n_] = run;
}

__global__ void k_scatter(const int* __restrict__ dst, int* __restrict__ cursor,
                          int* __restrict__ eid, int e_) {
  int e = blockIdx.x * blockDim.x + threadIdx.x;
  if (e < e_) {
    int p = atomicAdd(&cursor[dst[e]], 1);
    eid[p] = e;
  }
}

// ---------------- weight pack: Wt[n][k] = concat(wq|wk|wv|ws)[k][n], bf16 ----------------
template <int K>
__global__ void k_pack(const float* __restrict__ wq, const float* __restrict__ bq,
                       const float* __restrict__ wk, const float* __restrict__ bk,
                       const float* __restrict__ wv, const float* __restrict__ bv,
                       const float* __restrict__ ws, const float* __restrict__ bs,
                       __hip_bfloat16* __restrict__ Wt, float* __restrict__ biasp) {
  int n = blockIdx.x * 128 + threadIdx.x;  // 0..3327
  int k = blockIdx.y;                      // 0..K-1
  const float* w; const float* b; int off; int M;
  if (n < 1024)      { w = wq; b = bq; off = n;        M = 1024; }
  else if (n < 2048) { w = wk; b = bk; off = n - 1024; M = 1024; }
  else if (n < 3072) { w = wv; b = bv; off = n - 2048; M = 1024; }
  else               { w = ws; b = bs; off = n - 3072; M = 256;  }
  Wt[(size_t)n * K + k] = __float2bfloat16(w[(size_t)k * M + off]);
  if (k == 0) biasp[n] = b[off];
}

// ---------------- per-wave barrier-free MFMA GEMM -> q/k/v fp8 | skip bf16 ----------------
// One 64-thread wave per block. B-panel (64 cols x K) resident in registers.
// A streams through wave-private LDS double-buffer via global_load_lds with
// counted vmcnt (no __syncthreads anywhere). XOR-swizzled A layout (pre-swizzled
// global source + swizzled ds_read; LDS dest linear).
template <int K>
__global__ __launch_bounds__(64, 2) void k_gemm_pw(
    const __hip_bfloat16* __restrict__ X, const __hip_bfloat16* __restrict__ Wt,
    const float* __restrict__ biasp,
    unsigned char* __restrict__ qb, unsigned char* __restrict__ kb,
    unsigned char* __restrict__ vb, __hip_bfloat16* __restrict__ skipb,
    int nrows, int NCB, int NCH, int TPC, int RT) {
  __shared__ char lds[16384 + 2304];  // 2 x 8KB A dbuf + 16x144B epilogue scratch
  const int l = threadIdx.x;          // 0..63

  // XCD grouping: blocks on one XCD share a row-chunk's A panel.
  const int nwg = NCB * NCH;          // 2080, divisible by 8
  const int per = nwg >> 3;
  const int w = (blockIdx.x & 7) * per + (blockIdx.x >> 3);
  const int chunk = w / NCB;
  const int ct = w % NCB;
  const int bn = ct * 64;
  const int t0 = chunk * TPC;
  int t1 = t0 + TPC; if (t1 > RT) t1 = RT;
  constexpr int KT = K / 64;          // BK=64 chunks per tile
  constexpr int NS = K / 32;          // k-steps of 32 (b-frag count per n)

  const int lm = l & 15, lk = l >> 4;

  // ---- B panel -> registers (once per block) ----
  short8 bfr[4 * NS];
  {
    const __hip_bfloat16* bp = Wt + (size_t)(bn + lm) * K + lk * 8;
#pragma unroll
    for (int n = 0; n < 4; ++n)
#pragma unroll
      for (int s = 0; s < NS; ++s)
        bfr[n * NS + s] = *(const short8*)(bp + (size_t)n * 16 * K + s * 32);
  }
  float bia[4];
#pragma unroll
  for (int n = 0; n < 4; ++n) bia[n] = biasp[bn + n * 16 + lm];

  // output routing (uniform per block)
  unsigned char* dst8 = nullptr; int cb8 = 0;
  if (bn < 1024)      { dst8 = qb; cb8 = bn; }
  else if (bn < 2048) { dst8 = kb; cb8 = bn - 1024; }
  else if (bn < 3072) { dst8 = vb; cb8 = bn - 2048; }

  // ---- A staging (swizzled source, linear LDS dest) ----
  const int jrow = l >> 3;                     // 0..7 (row within 8-row group)
  const int cslot = (l & 7) ^ jrow;            // inverse-swizzled 16B chunk
  auto STAGE = [&](int buf, int t, int kt) {
    char* db = lds + buf * 8192;
#pragma unroll
    for (int j = 0; j < 8; ++j) {
      int r = t * 64 + j * 8 + jrow;
      if (r >= nrows) r = nrows - 1;
      gld16(X + (size_t)r * K + kt * 64 + cslot * 8, db + j * 1024 + l * 16);
    }
  };

  int buf = 0;
  STAGE(0, t0, 0);
  for (int t = t0; t < t1; ++t) {
    f32x4 acc[4][4] = {};
#pragma unroll
    for (int kt = 0; kt < KT; ++kt) {
      // prefetch next chunk (next kt, or next tile's chunk 0; dummy at very end)
      int nt = t, nk = kt + 1;
      if (nk == KT) { nt = (t + 1 < t1) ? t + 1 : t; nk = 0; }
      STAGE(buf ^ 1, nt, nk);
      asm volatile("s_waitcnt vmcnt(8)" ::: "memory");  // current chunk resident
      const char* db = lds + buf * 8192;
#pragma unroll
      for (int s2 = 0; s2 < 2; ++s2) {
        short8 a[4];
#pragma unroll
        for (int m = 0; m < 4; ++m) {
          int row = m * 16 + lm;
          a[m] = *(const short8*)(db + row * 128 + (((s2 * 4 + lk) ^ (lm & 7)) * 16));
        }
#pragma unroll
        for (int m = 0; m < 4; ++m)
#pragma unroll
          for (int n = 0; n < 4; ++n)
            acc[m][n] = __builtin_amdgcn_mfma_f32_16x16x32_bf16(
                a[m], bfr[n * NS + kt * 2 + s2], acc[m][n], 0, 0, 0);
      }
      buf ^= 1;
    }

    // ---- epilogue: 16 rows at a time through wave-private scratch ----
    char* sc = lds + 16384;
    const int tbase = t * 64;
    const int srow = l >> 2, qc = l & 3;
#pragma unroll
    for (int m = 0; m < 4; ++m) {
#pragma unroll
      for (int n = 0; n < 4; ++n)
#pragma unroll
        for (int r = 0; r < 4; ++r)
          *(__hip_bfloat16*)(sc + (lk * 4 + r) * 144 + (n * 16 + lm) * 2) =
              __float2bfloat16(acc[m][n][r] + bia[n]);
      const char* sr = sc + srow * 144 + qc * 32;
      short8 ta = *(const short8*)(sr);
      short8 tb = *(const short8*)(sr + 16);
      int grow = tbase + m * 16 + srow;
      if (grow < nrows) {
        if (dst8 != nullptr) {
          uint4 d;
          d.x = fp8pack4(bf2f((unsigned short)ta[0]), bf2f((unsigned short)ta[1]),
                         bf2f((unsigned short)ta[2]), bf2f((unsigned short)ta[3]));
          d.y = fp8pack4(bf2f((unsigned short)ta[4]), bf2f((unsigned short)ta[5]),
                         bf2f((unsigned short)ta[6]), bf2f((unsigned short)ta[7]));
          d.z = fp8pack4(bf2f((unsigned short)tb[0]), bf2f((unsigned short)tb[1]),
                         bf2f((unsigned short)tb[2]), bf2f((unsigned short)tb[3]));
          d.w = fp8pack4(bf2f((unsigned short)tb[4]), bf2f((unsigned short)tb[5]),
                         bf2f((unsigned short)tb[6]), bf2f((unsigned short)tb[7]));
          *(uint4*)(dst8 + (size_t)grow * 1024 + cb8 + qc * 16) = d;
        } else {
          __hip_bfloat16* sp = skipb + (size_t)grow * HIDC + (bn - 3072) + qc * 16;
          *(short8*)(sp) = ta;
          *(short8*)(sp + 8) = tb;
        }
      }
    }
  }
  asm volatile("s_waitcnt vmcnt(0)" ::: "memory");  // drain dangling prefetch
}

// ---------------- fused single-pass attention (fp8 q/k/v, bf16 skip) ----------------
__global__ __launch_bounds__(256) void k_attn(
    const unsigned char* __restrict__ qb, const unsigned char* __restrict__ kb,
    const unsigned char* __restrict__ vb,
    const int* __restrict__ offs, const int* __restrict__ eid,
    const int* __restrict__ src, const __hip_bfloat16* __restrict__ skipb,
    __hip_bfloat16* __restrict__ outb, float* __restrict__ outf) {
  int n = blockIdx.x;
  int s0 = offs[n], s1 = offs[n + 1];
  int deg = s1 - s0;
  int tid = threadIdx.x;
  if (deg == 0) {  // out = skip
    if (tid < 64) {
      int c = tid * 4;
      ushort4 sv = *(const ushort4*)((const ushort*)skipb + (size_t)n * HIDC + c);
      if (outb != nullptr) *(ushort4*)((ushort*)outb + (size_t)n * HIDC + c) = sv;
      if (outf != nullptr) {
        float* xr = outf + (size_t)n * HIDC + c;
        xr[0] = bf2f(sv.x); xr[1] = bf2f(sv.y); xr[2] = bf2f(sv.z); xr[3] = bf2f(sv.w);
      }
    }
    return;
  }
  __shared__ int ses[CAPD];
  __shared__ float red[NH][HIDC];
  int h = tid >> 6, lane = tid & 63;
  int dc = deg < CAPD ? deg : CAPD;
  for (int i = tid; i < dc; i += 256) ses[i] = src[eid[s0 + i]];
  __syncthreads();

  const int hc = h * HIDC;
  int c = lane * 4;
  unsigned qu = *(const unsigned*)(qb + (size_t)n * 1024 + hc + c);
  f32x2 q01 = __builtin_amdgcn_cvt_pk_f32_fp8(qu, false);
  f32x2 q23 = __builtin_amdgcn_cvt_pk_f32_fp8(qu, true);
  float qx = q01.x, qy = q01.y, qz = q23.x, qw = q23.y;

  float denom = 0.f;
  float4 acc = make_float4(0.f, 0.f, 0.f, 0.f);
  // 2-deep software pipeline over the serial edge loop
  int sc0 = ses[0];
  unsigned ku0 = *(const unsigned*)(kb + (size_t)sc0 * 1024 + hc + c);
  unsigned vu0 = *(const unsigned*)(vb + (size_t)sc0 * 1024 + hc + c);
  for (int i = 0; i < deg; ++i) {
    unsigned ku1 = 0, vu1 = 0;
    if (i + 1 < deg) {
      int s1i = (i + 1 < CAPD) ? ses[i + 1] : src[eid[s0 + i + 1]];
      ku1 = *(const unsigned*)(kb + (size_t)s1i * 1024 + hc + c);
      vu1 = *(const unsigned*)(vb + (size_t)s1i * 1024 + hc + c);
    }
    f32x2 k01 = __builtin_amdgcn_cvt_pk_f32_fp8(ku0, false);
    f32x2 k23 = __builtin_amdgcn_cvt_pk_f32_fp8(ku0, true);
    float p = qx * k01.x + qy * k01.y + qz * k23.x + qw * k23.y;
#pragma unroll
    for (int off = 32; off > 0; off >>= 1) p += __shfl_xor(p, off);
    float wgt = __expf(p * 0.0625f);
    denom += wgt;
    f32x2 v01 = __builtin_amdgcn_cvt_pk_f32_fp8(vu0, false);
    f32x2 v23 = __builtin_amdgcn_cvt_pk_f32_fp8(vu0, true);
    acc.x = fmaf(wgt, v01.x, acc.x);
    acc.y = fmaf(wgt, v01.y, acc.y);
    acc.z = fmaf(wgt, v23.x, acc.z);
    acc.w = fmaf(wgt, v23.y, acc.w);
    ku0 = ku1; vu0 = vu1;
  }
  float dinv = 1.f / (denom + 1e-16f);
  red[h][c + 0] = acc.x * dinv;
  red[h][c + 1] = acc.y * dinv;
  red[h][c + 2] = acc.z * dinv;
  red[h][c + 3] = acc.w * dinv;
  __syncthreads();
  if (tid < 64) {
    int c0 = tid * 4;
    ushort4 sv = *(const ushort4*)((const ushort*)skipb + (size_t)n * HIDC + c0);
    float sk[4] = {bf2f(sv.x), bf2f(sv.y), bf2f(sv.z), bf2f(sv.w)};
#pragma unroll
    for (int j = 0; j < 4; ++j) {
      float m = (red[0][c0 + j] + red[1][c0 + j] + red[2][c0 + j] + red[3][c0 + j]) * 0.25f;
      float val = m + sk[j];
      if (outb != nullptr) ((ushort*)outb)[(size_t)n * HIDC + c0 + j] = (ushort)(__bfloat16_as_ushort(__float2bfloat16(val)));
      if (outf != nullptr) outf[(size_t)n * HIDC + c0 + j] = val;
    }
  }
}

// ---------------- batch norm stats ----------------
__global__ void k_bnstats(const float* __restrict__ x, float* __restrict__ sums,
                          float* __restrict__ sumsq, int n_) {
  int t = threadIdx.x;
  float s = 0.f, s2 = 0.f;
  for (int r = blockIdx.x; r < n_; r += gridDim.x) {
    float vv = x[(size_t)r * HIDC + t];
    s += vv; s2 += vv * vv;
  }
  atomicAdd(&sums[t], s);
  atomicAdd(&sumsq[t], s2);
}

// ---------------- BN apply (stats inline) + linear head + softmax + rsu row ------
__global__ __launch_bounds__(256) void k_final(
    const float* __restrict__ x, const float* __restrict__ sums, const float* __restrict__ sumsq,
    const float* __restrict__ gamma, const float* __restrict__ beta,
    const float* __restrict__ lw, const float* __restrict__ lb,
    float* __restrict__ out, int n_) {
  int sub = threadIdx.x >> 6, lane = threadIdx.x & 63;
  int n = blockIdx.x * 4 + sub;
  if (n >= n_) return;
  int c = lane * 4;
  float4 sm  = *(const float4*)(sums + c);
  float4 sq  = *(const float4*)(sumsq + c);
  const float inv_n = 1.f / (float)n_;
  float mu0 = sm.x * inv_n, mu1 = sm.y * inv_n, mu2 = sm.z * inv_n, mu3 = sm.w * inv_n;
  float r0 = 1.f / sqrtf(fmaxf(sq.x * inv_n - mu0 * mu0, 0.f) + 1e-5f);
  float r1 = 1.f / sqrtf(fmaxf(sq.y * inv_n - mu1 * mu1, 0.f) + 1e-5f);
  float r2 = 1.f / sqrtf(fmaxf(sq.z * inv_n - mu2 * mu2, 0.f) + 1e-5f);
  float r3 = 1.f / sqrtf(fmaxf(sq.w * inv_n - mu3 * mu3, 0.f) + 1e-5f);
  const float* xr = x + (size_t)n * HIDC;
  float4 xv = *(const float4*)(xr + c);
  float4 gv = *(const float4*)(gamma + c);
  float4 bv = *(const float4*)(beta + c);
  float y0 = gv.x * (xv.x - mu0) * r0 + bv.x;
  float y1 = gv.y * (xv.y - mu1) * r1 + bv.y;
  float y2 = gv.z * (xv.z - mu2) * r2 + bv.z;
  float y3 = gv.w * (xv.w - mu3) * r3 + bv.w;
  float4 wa = *(const float4*)(lw + (size_t)c * 2);
  float4 wb = *(const float4*)(lw + (size_t)c * 2 + 4);
  float p0 = y0 * wa.x + y1 * wa.z + y2 * wb.x + y3 * wb.z;
  float p1 = y0 * wa.y + y1 * wa.w + y2 * wb.y + y3 * wb.w;
#pragma unroll
  for (int off = 32; off > 0; off >>= 1) {
    p0 += __shfl_xor(p0, off);
    p1 += __shfl_xor(p1, off);
  }
  if (n == 0) *(float4*)(out + (size_t)NN * 2 + c) = make_float4(y0, y1, y2, y3);
  if (lane == 0) {
    float l0 = fmaxf(p0 + lb[0], 0.f);
    float l1 = fmaxf(p1 + lb[1], 0.f);
    float m = fmaxf(l0, l1);
    float e0 = expf(l0 - m), e1 = expf(l1 - m);
    float inv = 1.f / (e0 + e1);
    out[(size_t)n * 2 + 0] = e0 * inv;
    out[(size_t)n * 2 + 1] = e1 * inv;
  }
}

// ---------------- launch ----------------
extern "C" void kernel_launch(void* const* d_in, const int* in_sizes, int n_in,
                              void* d_out, int out_size, void* d_ws, size_t ws_size,
                              hipStream_t stream) {
  const float* x0  = (const float*)d_in[0];
  const int*   ei  = (const int*)d_in[1];
  const float* wq1 = (const float*)d_in[2];  const float* bq1 = (const float*)d_in[3];
  const float* wk1 = (const float*)d_in[4];  const float* bk1 = (const float*)d_in[5];
  const float* wv1 = (const float*)d_in[6];  const float* bv1 = (const float*)d_in[7];
  const float* ws1 = (const float*)d_in[8];  const float* bs1 = (const float*)d_in[9];
  const float* wq2 = (const float*)d_in[10]; const float* bq2 = (const float*)d_in[11];
  const float* wk2 = (const float*)d_in[12]; const float* bk2 = (const float*)d_in[13];
  const float* wv2 = (const float*)d_in[14]; const float* bv2 = (const float*)d_in[15];
  const float* ws2 = (const float*)d_in[16]; const float* bs2 = (const float*)d_in[17];
  const float* gam = (const float*)d_in[18]; const float* bet = (const float*)d_in[19];
  const float* lw  = (const float*)d_in[20]; const float* lb  = (const float*)d_in[21];
  const int* srcv = ei;
  const int* dstv = ei + NE;

  char* p = (char*)d_ws;
  auto take = [&](size_t bytes) {
    char* r = p;
    p += (bytes + 255) & ~(size_t)255;
    return r;
  };
  unsigned char* qbuf = (unsigned char*)take((size_t)NN * 1024);
  unsigned char* kbuf = (unsigned char*)take((size_t)NN * 1024);
  unsigned char* vbuf = (unsigned char*)take((size_t)NN * 1024);
  __hip_bfloat16* skipb = (__hip_bfloat16*)take((size_t)NN * HIDC * 2);
  __hip_bfloat16* x0b = (__hip_bfloat16*)take((size_t)NN * FIN * 2);
  __hip_bfloat16* x2b = (__hip_bfloat16*)take((size_t)NN * HIDC * 2);
  __hip_bfloat16* Wt  = (__hip_bfloat16*)take((size_t)NOUT * HIDC * 2);
  float* x3    = (float*)take((size_t)NN * HIDC * 4);
  float* biasp = (float*)take((size_t)NOUT * 4);
  float* bnbuf = (float*)take(2 * HIDC * 4);
  int* deg    = (int*)take((size_t)NN * 4);
  int* offs   = (int*)take((size_t)(NN + 1) * 4);
  int* cursor = (int*)take((size_t)NN * 4);
  int* eidb   = (int*)take((size_t)NE * 4);
  if ((size_t)(p - (char*)d_ws) > ws_size) return;

  float* sums  = bnbuf;
  float* sumsq = bnbuf + HIDC;

  hipMemsetAsync(deg, 0, (size_t)NN * 4, stream);
  hipMemsetAsync(bnbuf, 0, 2 * HIDC * 4, stream);
  k_prep<<<(NN * FIN + 255) / 256, 256, 0, stream>>>(x0, x0b, dstv, deg);
  k_scan<<<1, 1024, 0, stream>>>(deg, offs, cursor, NN);
  k_scatter<<<(NE + 255) / 256, 256, 0, stream>>>(dstv, cursor, eidb, NE);

  const int RT  = (NN + 63) / 64;   // 313 row tiles (64 rows each)
  const int NCB = NOUT / 64;        // 52 col tiles (64 cols each)
  const int NCH = 40;               // row chunks
  const int TPC = (RT + NCH - 1) / NCH;  // 8 tiles per chunk
  const int GRID = NCB * NCH;       // 2080 single-wave blocks
  // ---- layer 1 ----
  k_pack<FIN><<<dim3(NOUT / 128, FIN), 128, 0, stream>>>(wq1, bq1, wk1, bk1, wv1, bv1, ws1, bs1, Wt, biasp);
  k_gemm_pw<FIN><<<GRID, 64, 0, stream>>>(x0b, Wt, biasp, qbuf, kbuf, vbuf, skipb, NN, NCB, NCH, TPC, RT);
  k_attn<<<NN, 256, 0, stream>>>(qbuf, kbuf, vbuf, offs, eidb, srcv, skipb, x2b, nullptr);
  // ---- layer 2 ----
  k_pack<HIDC><<<dim3(NOUT / 128, HIDC), 128, 0, stream>>>(wq2, bq2, wk2, bk2, wv2, bv2, ws2, bs2, Wt, biasp);
  k_gemm_pw<HIDC><<<GRID, 64, 0, stream>>>(x2b, Wt, biasp, qbuf, kbuf, vbuf, skipb, NN, NCB, NCH, TPC, RT);
  k_attn<<<NN, 256, 0, stream>>>(qbuf, kbuf, vbuf, offs, eidb, srcv, skipb, nullptr, x3);
  // ---- BN + head ----
  k_bnstats<<<256, 256, 0, stream>>>(x3, sums, sumsq, NN);
  k_final<<<(NN + 3) / 4, 256, 0, stream>>>(x3, sums, sumsq, gam, bet, lw, lb, (float*)d_out, NN);
}